// Round 2
// baseline (1804.637 us; speedup 1.0000x reference)
//
#include <hip/hip_runtime.h>

// EncoderGRUODE: B=256, T=512, D_IN=64, H=128
// R4: R3's two diseases removed, structure kept.
//  - R3 post-mortem: (a) sWih in LDS -> row-indexed reads, stride 17*f4 == 16
//    words mod 32 -> ~32-way bank conflict, 1.0e8 conflict cycles; (b) VGPR=64
//    reported -> allocator parked weights in AGPRs, VALU-busy time 594->1016us.
//  - Fix (a): NO weights in LDS. All LDS data reads are broadcast patterns
//    (address depends only on ks/ko, never j) -> zero conflicts by design.
//  - Fix (b): at 1024 threads the full weight set is 96 VGPR/lane
//    (Wn 16 + Whh 48 + Wih 24 + Wo 8); working set trimmed to ~25 regs by
//    preloading dt[]/mask[] into LDS once (kills tp/mask prefetch regs and
//    per-step global loads; per-step dt/mask reads are LDS broadcasts).
//  - Keep: 5 barriers/step (out-matvec paired with k1, input dots with k3),
//    one-step-ahead x prefetch, 4 waves/SIMD occupancy.
// Predicted: conflicts ~0, VGPR ~128 (no AGPR churn), VALUBusy 60-70%,
// dur 1617 -> 750-950us (baseline 1227).

#define NB    256
#define TB    1024
#define TSTEP 512
#define DIN   64
#define HD    128

typedef float v2f __attribute__((ext_vector_type(2)));

__device__ __forceinline__ float fast_tanh(float v) {
    float e = __expf(2.0f * v);
    return 1.0f - 2.0f / (e + 1.0f);
}
__device__ __forceinline__ float fast_sigmoid(float v) {
    return 1.0f / (1.0f + __expf(-v));
}

// 8-lane butterfly: DPP xor1, xor2 + ds_swizzle xor4. All 8 lanes get the sum.
__device__ __forceinline__ float red8(float v) {
    v += __int_as_float(__builtin_amdgcn_update_dpp(
            0, __float_as_int(v), 0xB1, 0xF, 0xF, true)); // quad_perm xor 1
    v += __int_as_float(__builtin_amdgcn_update_dpp(
            0, __float_as_int(v), 0x4E, 0xF, 0xF, true)); // quad_perm xor 2
    v += __int_as_float(__builtin_amdgcn_ds_swizzle(__float_as_int(v), 0x101F)); // xor 4
    return v;
}
__device__ __forceinline__ float red16(float v) {
    v = red8(v);
    v += __int_as_float(__builtin_amdgcn_ds_swizzle(__float_as_int(v), 0x201F)); // xor 8
    return v;
}

__global__ __launch_bounds__(TB, 4) void gruode_kernel(
    const float* __restrict__ x,         // [B, T, DIN]
    const float* __restrict__ tp,        // [B, T] (row 0 used)
    const int*   __restrict__ samp_mask, // [T]
    const float* __restrict__ W_ih,      // [3H, DIN]
    const float* __restrict__ W_hh,      // [3H, H]
    const float* __restrict__ b_ih,      // [3H]
    const float* __restrict__ b_hh,      // [3H]
    const float* __restrict__ W_node,    // [H, H]
    const float* __restrict__ b_node,    // [H]
    const float* __restrict__ W_out,     // [DIN, H]
    const float* __restrict__ b_out,     // [DIN]
    float*       __restrict__ out)       // [B*T, DIN]
{
    const int t   = threadIdx.x;
    const int b   = blockIdx.x;
    const int j   = t >> 3;        // hidden row owned by this 8-lane group
    const int ks  = t & 7;         // k-slice within row group
    const int j64 = t >> 4;        // output row owned by this 16-lane group
    const int ko  = t & 15;        // k-slice within out group

    __shared__ __align__(16) float sh_h [HD];
    __shared__ __align__(16) float sh_t0[HD];
    __shared__ __align__(16) float sh_t1[HD];
    __shared__ __align__(16) float sh_in[DIN];
    __shared__ __align__(16) float sh_po[DIN];
    __shared__ float sh_dt[TSTEP];
    __shared__ int   sh_mk[TSTEP];

    const float4* Wn4  = (const float4*)W_node;  // [128][32 f4]
    const float4* Whh4 = (const float4*)W_hh;    // [384][32 f4]
    const float4* Wih4 = (const float4*)W_ih;    // [384][16 f4]
    const float4* Wo4  = (const float4*)W_out;   // [64][32 f4]

    // ---- all weights -> registers (96 VGPRs/lane at 1024 threads) ----
    v2f Wn[8], Whr[8], Whz[8], Whn[8];           // 16 floats each
    #pragma unroll
    for (int i = 0; i < 4; ++i) {
        float4 w;
        w = Wn4 [j*32 + i*8 + ks];          Wn [2*i] = (v2f){w.x, w.y}; Wn [2*i+1] = (v2f){w.z, w.w};
        w = Whh4[(0*HD + j)*32 + i*8 + ks]; Whr[2*i] = (v2f){w.x, w.y}; Whr[2*i+1] = (v2f){w.z, w.w};
        w = Whh4[(1*HD + j)*32 + i*8 + ks]; Whz[2*i] = (v2f){w.x, w.y}; Whz[2*i+1] = (v2f){w.z, w.w};
        w = Whh4[(2*HD + j)*32 + i*8 + ks]; Whn[2*i] = (v2f){w.x, w.y}; Whn[2*i+1] = (v2f){w.z, w.w};
    }
    v2f Wir[4], Wiz[4], Win[4], Wo[4];           // 8 floats each
    #pragma unroll
    for (int i = 0; i < 2; ++i) {
        float4 w;
        w = Wih4[(0*HD + j)*16 + i*8 + ks]; Wir[2*i] = (v2f){w.x, w.y}; Wir[2*i+1] = (v2f){w.z, w.w};
        w = Wih4[(1*HD + j)*16 + i*8 + ks]; Wiz[2*i] = (v2f){w.x, w.y}; Wiz[2*i+1] = (v2f){w.z, w.w};
        w = Wih4[(2*HD + j)*16 + i*8 + ks]; Win[2*i] = (v2f){w.x, w.y}; Win[2*i+1] = (v2f){w.z, w.w};
        w = Wo4 [j64*32 + i*16 + ko];       Wo [2*i] = (v2f){w.x, w.y}; Wo [2*i+1] = (v2f){w.z, w.w};
    }
    // Pin once: opaque to rematerialization (prevents R1's L2 re-fetch).
    #pragma unroll
    for (int i = 0; i < 8; ++i) {
        asm volatile("" : "+v"(Wn[i]));  asm volatile("" : "+v"(Whr[i]));
        asm volatile("" : "+v"(Whz[i])); asm volatile("" : "+v"(Whn[i]));
    }
    #pragma unroll
    for (int i = 0; i < 4; ++i) {
        asm volatile("" : "+v"(Wir[i])); asm volatile("" : "+v"(Wiz[i]));
        asm volatile("" : "+v"(Win[i])); asm volatile("" : "+v"(Wo[i]));
    }

    const float bn   = b_node[j];
    const float br   = b_ih[0*HD + j] + b_hh[0*HD + j];
    const float bz   = b_ih[1*HD + j] + b_hh[1*HD + j];
    const float bi_n = b_ih[2*HD + j];
    const float bh_n = b_hh[2*HD + j];
    const float bo   = b_out[j64];

    if (t < HD) sh_h[t] = 0.0f;

    // dt/mask tables -> LDS once (per-step reads are uniform broadcasts)
    if (t < TSTEP) {
        float tc = tp[t];
        float tq = (t == 0) ? tc - 0.01f : tp[t - 1];
        sh_dt[t] = tc - tq;
        sh_mk[t] = samp_mask[t];
    }

    const float* xbase = x   + (size_t)b * TSTEP * DIN;
    float*       obase = out + (size_t)b * TSTEP * DIN;
    float xr = (t < DIN) ? xbase[t] : 0.0f;

    __syncthreads();

    const float4* h4  = (const float4*)sh_h;
    const float4* t04 = (const float4*)sh_t0;
    const float4* t14 = (const float4*)sh_t1;
    const float4* in4 = (const float4*)sh_in;

    // 1/8-sliced packed dot over a 128-float LDS vector (broadcast reads)
    auto hdot = [&](const v2f (&w)[8], const float4* buf) -> float {
        v2f a0 = {0.f, 0.f}, a1 = {0.f, 0.f};
        #pragma unroll
        for (int i = 0; i < 4; ++i) {
            float4 v = buf[i*8 + ks];
            a0 += w[2*i]   * (v2f){v.x, v.y};
            a1 += w[2*i+1] * (v2f){v.z, v.w};
        }
        v2f a = a0 + a1;
        return a.x + a.y;
    };

    float hj = 0.0f;   // h carried in registers (all 8 group lanes hold row j)

    #pragma unroll 1
    for (int s = 0; s < TSTEP; ++s) {
        const float dt = sh_dt[s];          // uniform broadcast
        const int   mc = sh_mk[s];

        // ---- P1: k1 dot + output matvec of previous h_new (both read sh_h) --
        float k1 = fast_tanh(red8(hdot(Wn, h4)) + bn);
        {
            v2f ao = {0.f, 0.f};
            #pragma unroll
            for (int i = 0; i < 2; ++i) {
                float4 v = h4[i*16 + ko];
                ao += Wo[2*i]   * (v2f){v.x, v.y};
                ao += Wo[2*i+1] * (v2f){v.z, v.w};
            }
            float o = red16(ao.x + ao.y) + bo;   // = h_new(s-1)@Wo^T + bo
            if (ko == 0) {
                sh_po[j64] = o;                  // prev_out for this step's input
                if (s > 0) obase[(size_t)(s - 1) * DIN + j64] = o;
            }
        }
        if (ks == 0) sh_t0[j] = fmaf(0.5f * dt, k1, hj);
        __syncthreads();                                   // B1

        // ---- P2: k2 dot; build input vec; prefetch next-step x ----
        if (t < DIN) sh_in[t] = mc ? xr : sh_po[t];
        float k2 = fast_tanh(red8(hdot(Wn, t04)) + bn);
        if (ks == 0) sh_t1[j] = fmaf(0.5f * dt, k2, hj);
        {
            const int sn = (s + 1 < TSTEP) ? s + 1 : s;
            if (t < DIN) xr = xbase[(size_t)sn * DIN + t];
        }
        __syncthreads();                                   // B2

        // ---- P3: k3 dot + input-gate dots (weights in regs) ----
        float k3 = fast_tanh(red8(hdot(Wn, t14)) + bn);
        float crs, czs, cns;
        {
            v2f cr = {0.f,0.f}, cz = {0.f,0.f}, cn = {0.f,0.f};
            #pragma unroll
            for (int i = 0; i < 2; ++i) {
                float4 v = in4[i*8 + ks];
                v2f lo = {v.x, v.y}, hi = {v.z, v.w};
                cr += Wir[2*i] * lo; cr += Wir[2*i+1] * hi;
                cz += Wiz[2*i] * lo; cz += Wiz[2*i+1] * hi;
                cn += Win[2*i] * lo; cn += Win[2*i+1] * hi;
            }
            crs = red8(cr.x + cr.y);
            czs = red8(cz.x + cz.y);
            cns = red8(cn.x + cn.y);
        }
        if (ks == 0) sh_t0[j] = fmaf(dt, k3, hj);
        __syncthreads();                                   // B3

        // ---- P4: k4 dot; h_ode ----
        float k4 = fast_tanh(red8(hdot(Wn, t04)) + bn);
        float hode = fmaf(dt * (1.0f / 6.0f),
                          (k1 + 2.0f * k2) + (2.0f * k3 + k4), hj);
        if (ks == 0) sh_t1[j] = hode;                      // t1 = h_ode vector
        __syncthreads();                                   // B4

        // ---- P5: GRU hidden-gate dots + combine ----
        v2f ar = {0.f,0.f}, az = {0.f,0.f}, an = {0.f,0.f};
        #pragma unroll
        for (int i = 0; i < 4; ++i) {
            float4 v = t14[i*8 + ks];
            v2f lo = {v.x, v.y}, hi = {v.z, v.w};
            ar += Whr[2*i] * lo; ar += Whr[2*i+1] * hi;
            az += Whz[2*i] * lo; az += Whz[2*i+1] * hi;
            an += Whn[2*i] * lo; an += Whn[2*i+1] * hi;
        }
        float rr  = fast_sigmoid(red8(ar.x + ar.y) + crs + br);
        float zz  = fast_sigmoid(red8(az.x + az.y) + czs + bz);
        float hnv = red8(an.x + an.y) + bh_n;
        float inv = cns + bi_n;
        float nn  = fast_tanh(fmaf(rr, hnv, inv));
        float hnew = fmaf(zz, hode - nn, nn);              // (1-z)n + z*h_ode
        hj = hnew;
        if (ks == 0) sh_h[j] = hnew;
        __syncthreads();                                   // B5
    }

    // ---- epilogue: out[T-1] = h_new(T-1) @ W_out^T + b_out ----
    {
        v2f ao = {0.f, 0.f};
        #pragma unroll
        for (int i = 0; i < 2; ++i) {
            float4 v = h4[i*16 + ko];
            ao += Wo[2*i]   * (v2f){v.x, v.y};
            ao += Wo[2*i+1] * (v2f){v.z, v.w};
        }
        float o = red16(ao.x + ao.y) + bo;
        if (ko == 0) obase[(size_t)(TSTEP - 1) * DIN + j64] = o;
    }
}

extern "C" void kernel_launch(void* const* d_in, const int* in_sizes, int n_in,
                              void* d_out, int out_size, void* d_ws, size_t ws_size,
                              hipStream_t stream) {
    (void)in_sizes; (void)n_in; (void)d_ws; (void)ws_size; (void)out_size;
    const float* x      = (const float*)d_in[0];
    const float* tp     = (const float*)d_in[1];
    const int*   mask   = (const int*)  d_in[2];
    const float* W_ih   = (const float*)d_in[3];
    const float* W_hh   = (const float*)d_in[4];
    const float* b_ih   = (const float*)d_in[5];
    const float* b_hh   = (const float*)d_in[6];
    const float* W_node = (const float*)d_in[7];
    const float* b_node = (const float*)d_in[8];
    const float* W_out  = (const float*)d_in[9];
    const float* b_out  = (const float*)d_in[10];
    float* outp = (float*)d_out;

    gruode_kernel<<<NB, TB, 0, stream>>>(x, tp, mask, W_ih, W_hh, b_ih, b_hh,
                                         W_node, b_node, W_out, b_out, outp);
}

// Round 3
// 1138.209 us; speedup vs baseline: 1.5855x; 1.5855x over previous
//
#include <hip/hip_runtime.h>

// EncoderGRUODE: B=256, T=512, D_IN=64, H=128
// R5: LDS-bandwidth attack. Model (validated against R2's counters):
//   R2 step = 5750cy: ~3400cy LDS return (390KB/step broadcast-amplified
//   ds_read_b128, 112 B/cy/CU) + ~2700cy VALU issue, poorly overlapped.
//   R3/R4 failed structurally: 1024thr can't hold the weights under the
//   128-reg/lane cap at 4 waves/SIMD (AGPR shuttle, VALU time 577->938us).
// Changes vs R2 (TB=512, 2 waves/SIMD, weights-in-regs kept):
//   - 2 rows x 16-float k-slice per lane (was 1x32): every loaded h-float
//     feeds 2 rows -> RK4 LDS traffic halves (256->128KB/step).
//   - out matvec re-sliced to the same ks*16 slice as k1: reuses k1's loaded
//     h values (zero extra LDS reads); out row = jp, plain red8.
//   - split-reduce: 2 DPP butterfly stages on both row-partials + one
//     cndmask'd xor4 exchange -> lanes ks<4 own rowA total, ks>=4 rowB.
//     Same op count as 2 reductions; transcendentals stay 1/lane/stage;
//     hj/k1..k3/hode carried single-width on owner lanes (ks&3)==0.
//   - total LDS ~215KB/step (~1900cy) vs R2 ~390KB (~3400cy).
// Predicted: VGPR ~128, Occupancy ~23%, VALUBusy 50-60%, dur -> 600-750us.

#define NB    256
#define TB    512
#define TSTEP 512
#define DIN   64
#define HD    128

typedef float v2f __attribute__((ext_vector_type(2)));

__device__ __forceinline__ float fast_tanh(float v) {
    float e = __expf(2.0f * v);
    return 1.0f - 2.0f / (e + 1.0f);
}
__device__ __forceinline__ float fast_sigmoid(float v) {
    return 1.0f / (1.0f + __expf(-v));
}

template<int PAT>
__device__ __forceinline__ float dpp_xadd(float v) {
    return v + __int_as_float(__builtin_amdgcn_update_dpp(
        0, __float_as_int(v), PAT, 0xF, 0xF, true));
}
template<int OFF>
__device__ __forceinline__ float swz(float v) {
    return __int_as_float(__builtin_amdgcn_ds_swizzle(__float_as_int(v), OFF));
}
// plain 8-lane all-lanes reduction (xor1, xor2, xor4)
__device__ __forceinline__ float red8(float v) {
    v = dpp_xadd<0xB1>(v);
    v = dpp_xadd<0x4E>(v);
    return v + swz<0x101F>(v);
}
// reduce two row-partials over the 8-lane group for the price of one:
// lanes with low=true end with rowA total, low=false with rowB total.
__device__ __forceinline__ float red8_split(float pA, float pB, bool low) {
    pA = dpp_xadd<0xB1>(pA);  pB = dpp_xadd<0xB1>(pB);
    pA = dpp_xadd<0x4E>(pA);  pB = dpp_xadd<0x4E>(pB);
    float keep = low ? pA : pB;
    float send = low ? pB : pA;
    return keep + swz<0x101F>(send);
}

__global__ __launch_bounds__(TB, 2) void gruode_kernel(
    const float* __restrict__ x,         // [B, T, DIN]
    const float* __restrict__ tp,        // [B, T] (row 0 used)
    const int*   __restrict__ samp_mask, // [T]
    const float* __restrict__ W_ih,      // [3H, DIN]
    const float* __restrict__ W_hh,      // [3H, H]
    const float* __restrict__ b_ih,      // [3H]
    const float* __restrict__ b_hh,      // [3H]
    const float* __restrict__ W_node,    // [H, H]
    const float* __restrict__ b_node,    // [H]
    const float* __restrict__ W_out,     // [DIN, H]
    const float* __restrict__ b_out,     // [DIN]
    float*       __restrict__ out)       // [B*T, DIN]
{
    const int t    = threadIdx.x;
    const int b    = blockIdx.x;
    const int jp   = t >> 3;              // row-pair index 0..63 (also out row)
    const int ks   = t & 7;               // 16-float k-slice 0..7
    const bool low = (ks & 4) == 0;       // owns rowA (2jp) vs rowB (2jp+1)
    const int jm   = 2 * jp + (ks >> 2);  // my hidden row after split-reduce
    const bool own = (ks & 3) == 0;       // writer lane for row jm

    __shared__ __align__(16) float sh_h [HD];
    __shared__ __align__(16) float sh_t0[HD];
    __shared__ __align__(16) float sh_t1[HD];
    __shared__ __align__(16) float sh_in[DIN];
    __shared__ __align__(16) float sh_po[DIN];
    __shared__ float sh_dt[TSTEP];
    __shared__ int   sh_mk[TSTEP];

    const float4* Wn4  = (const float4*)W_node;  // [128][32 f4]
    const float4* Whh4 = (const float4*)W_hh;    // [384][32 f4]
    const float4* Wih4 = (const float4*)W_ih;    // [384][16 f4]
    const float4* Wo4  = (const float4*)W_out;   // [64][32 f4]

    // ---- weights -> registers: 2 rows x 16-float slice (192 floats/lane) ----
    v2f WnA[8], WnB[8], WhrA[8], WhrB[8], WhzA[8], WhzB[8], WhnA[8], WhnB[8];
    #pragma unroll
    for (int ii = 0; ii < 4; ++ii) {
        float4 w;
        const int c = ks * 4 + ii;
        w = Wn4 [(2*jp  )*32 + c];        WnA [2*ii] = (v2f){w.x,w.y}; WnA [2*ii+1] = (v2f){w.z,w.w};
        w = Wn4 [(2*jp+1)*32 + c];        WnB [2*ii] = (v2f){w.x,w.y}; WnB [2*ii+1] = (v2f){w.z,w.w};
        w = Whh4[(0*HD + 2*jp  )*32 + c]; WhrA[2*ii] = (v2f){w.x,w.y}; WhrA[2*ii+1] = (v2f){w.z,w.w};
        w = Whh4[(0*HD + 2*jp+1)*32 + c]; WhrB[2*ii] = (v2f){w.x,w.y}; WhrB[2*ii+1] = (v2f){w.z,w.w};
        w = Whh4[(1*HD + 2*jp  )*32 + c]; WhzA[2*ii] = (v2f){w.x,w.y}; WhzA[2*ii+1] = (v2f){w.z,w.w};
        w = Whh4[(1*HD + 2*jp+1)*32 + c]; WhzB[2*ii] = (v2f){w.x,w.y}; WhzB[2*ii+1] = (v2f){w.z,w.w};
        w = Whh4[(2*HD + 2*jp  )*32 + c]; WhnA[2*ii] = (v2f){w.x,w.y}; WhnA[2*ii+1] = (v2f){w.z,w.w};
        w = Whh4[(2*HD + 2*jp+1)*32 + c]; WhnB[2*ii] = (v2f){w.x,w.y}; WhnB[2*ii+1] = (v2f){w.z,w.w};
    }
    v2f WirA[4], WirB[4], WizA[4], WizB[4], WinA[4], WinB[4], Wo[8];
    #pragma unroll
    for (int ii = 0; ii < 2; ++ii) {
        float4 w;
        const int c = ks * 2 + ii;
        w = Wih4[(0*HD + 2*jp  )*16 + c]; WirA[2*ii] = (v2f){w.x,w.y}; WirA[2*ii+1] = (v2f){w.z,w.w};
        w = Wih4[(0*HD + 2*jp+1)*16 + c]; WirB[2*ii] = (v2f){w.x,w.y}; WirB[2*ii+1] = (v2f){w.z,w.w};
        w = Wih4[(1*HD + 2*jp  )*16 + c]; WizA[2*ii] = (v2f){w.x,w.y}; WizA[2*ii+1] = (v2f){w.z,w.w};
        w = Wih4[(1*HD + 2*jp+1)*16 + c]; WizB[2*ii] = (v2f){w.x,w.y}; WizB[2*ii+1] = (v2f){w.z,w.w};
        w = Wih4[(2*HD + 2*jp  )*16 + c]; WinA[2*ii] = (v2f){w.x,w.y}; WinA[2*ii+1] = (v2f){w.z,w.w};
        w = Wih4[(2*HD + 2*jp+1)*16 + c]; WinB[2*ii] = (v2f){w.x,w.y}; WinB[2*ii+1] = (v2f){w.z,w.w};
    }
    #pragma unroll
    for (int ii = 0; ii < 4; ++ii) {      // out row jp, same ks*16 slice as k1
        float4 w = Wo4[jp*32 + ks*4 + ii];
        Wo[2*ii] = (v2f){w.x,w.y}; Wo[2*ii+1] = (v2f){w.z,w.w};
    }
    // Pin: opaque to rematerialization (prevents L2 re-fetch).
    #pragma unroll
    for (int ii = 0; ii < 8; ++ii) {
        asm volatile("" : "+v"(WnA[ii]));  asm volatile("" : "+v"(WnB[ii]));
        asm volatile("" : "+v"(WhrA[ii])); asm volatile("" : "+v"(WhrB[ii]));
        asm volatile("" : "+v"(WhzA[ii])); asm volatile("" : "+v"(WhzB[ii]));
        asm volatile("" : "+v"(WhnA[ii])); asm volatile("" : "+v"(WhnB[ii]));
        asm volatile("" : "+v"(Wo[ii]));
    }
    #pragma unroll
    for (int ii = 0; ii < 4; ++ii) {
        asm volatile("" : "+v"(WirA[ii])); asm volatile("" : "+v"(WirB[ii]));
        asm volatile("" : "+v"(WizA[ii])); asm volatile("" : "+v"(WizB[ii]));
        asm volatile("" : "+v"(WinA[ii])); asm volatile("" : "+v"(WinB[ii]));
    }

    // per-row biases for my row jm; out bias for row jp
    const float bn_s = b_node[jm];
    const float br_s = b_ih[0*HD + jm] + b_hh[0*HD + jm];
    const float bz_s = b_ih[1*HD + jm] + b_hh[1*HD + jm];
    const float bi_s = b_ih[2*HD + jm];
    const float bh_s = b_hh[2*HD + jm];
    const float bo   = b_out[jp];

    if (t < HD) sh_h[t] = 0.0f;
    {   // dt/mask tables -> LDS once (per-step reads are uniform broadcasts)
        float tc = tp[t];
        float tq = (t == 0) ? tc - 0.01f : tp[t - 1];
        sh_dt[t] = tc - tq;
        sh_mk[t] = samp_mask[t];
    }

    const float* xbase = x   + (size_t)b * TSTEP * DIN;
    float*       obase = out + (size_t)b * TSTEP * DIN;
    float xr = (t < DIN) ? xbase[t] : 0.0f;

    __syncthreads();

    const float4* h4  = (const float4*)sh_h;
    const float4* t04 = (const float4*)sh_t0;
    const float4* t14 = (const float4*)sh_t1;
    const float4* in4 = (const float4*)sh_in;

    // 2-row sliced dot over a 128-float LDS vector (4 b128 broadcast reads)
    auto dot2 = [&](const v2f (&wA)[8], const v2f (&wB)[8], const float4* buf,
                    float& rA, float& rB) {
        v2f aA = {0.f,0.f}, bA = {0.f,0.f}, aB = {0.f,0.f}, bB = {0.f,0.f};
        #pragma unroll
        for (int ii = 0; ii < 4; ++ii) {
            float4 v = buf[ks*4 + ii];
            v2f lo = {v.x, v.y}, hi = {v.z, v.w};
            aA += wA[2*ii] * lo;  bA += wA[2*ii+1] * hi;
            aB += wB[2*ii] * lo;  bB += wB[2*ii+1] * hi;
        }
        v2f sA = aA + bA, sB = aB + bB;
        rA = sA.x + sA.y;  rB = sB.x + sB.y;
    };

    float hj = 0.0f;   // my row's h (meaningful on owner lanes)

    #pragma unroll 1
    for (int s = 0; s < TSTEP; ++s) {
        const float dt = sh_dt[s];
        const int   mc = sh_mk[s];
        float k1, k2, k3;

        // ---- P1: k1 dot + out matvec sharing the same sh_h loads ----
        {
            float4 v0 = h4[ks*4+0], v1 = h4[ks*4+1], v2 = h4[ks*4+2], v3 = h4[ks*4+3];
            v2f l0 = {v0.x,v0.y}, u0 = {v0.z,v0.w};
            v2f l1 = {v1.x,v1.y}, u1 = {v1.z,v1.w};
            v2f l2 = {v2.x,v2.y}, u2 = {v2.z,v2.w};
            v2f l3 = {v3.x,v3.y}, u3 = {v3.z,v3.w};
            v2f aA = WnA[0]*l0 + WnA[1]*u0 + WnA[2]*l1 + WnA[3]*u1
                   + WnA[4]*l2 + WnA[5]*u2 + WnA[6]*l3 + WnA[7]*u3;
            v2f aB = WnB[0]*l0 + WnB[1]*u0 + WnB[2]*l1 + WnB[3]*u1
                   + WnB[4]*l2 + WnB[5]*u2 + WnB[6]*l3 + WnB[7]*u3;
            v2f ao = Wo[0]*l0 + Wo[1]*u0 + Wo[2]*l1 + Wo[3]*u1
                   + Wo[4]*l2 + Wo[5]*u2 + Wo[6]*l3 + Wo[7]*u3;
            k1 = fast_tanh(red8_split(aA.x + aA.y, aB.x + aB.y, low) + bn_s);
            float o = red8(ao.x + ao.y) + bo;   // = h(s-1)@Wo^T + bo
            if (ks == 0) {
                sh_po[jp] = o;                   // prev_out for this step
                if (s > 0) obase[(size_t)(s - 1) * DIN + jp] = o;
            }
            if (own) sh_t0[jm] = fmaf(0.5f * dt, k1, hj);
        }
        __syncthreads();                                   // B1

        // ---- P2: build input vec; k2 dot; prefetch next-step x ----
        if (t < DIN) sh_in[t] = mc ? xr : sh_po[t];
        {
            float rA, rB;
            dot2(WnA, WnB, t04, rA, rB);
            k2 = fast_tanh(red8_split(rA, rB, low) + bn_s);
            if (own) sh_t1[jm] = fmaf(0.5f * dt, k2, hj);
        }
        {
            const int sn = (s + 1 < TSTEP) ? s + 1 : s;
            if (t < DIN) xr = xbase[(size_t)sn * DIN + t];
        }
        __syncthreads();                                   // B2

        // ---- P3: k3 dot + input-gate partial dots (reduction deferred) ----
        float crA, crB, czA, czB, cnA, cnB;
        {
            float rA, rB;
            dot2(WnA, WnB, t14, rA, rB);
            k3 = fast_tanh(red8_split(rA, rB, low) + bn_s);

            float4 v0 = in4[ks*2+0], v1 = in4[ks*2+1];
            v2f lo0 = {v0.x,v0.y}, hi0 = {v0.z,v0.w};
            v2f lo1 = {v1.x,v1.y}, hi1 = {v1.z,v1.w};
            v2f cr0 = WirA[0]*lo0 + WirA[1]*hi0 + WirA[2]*lo1 + WirA[3]*hi1;
            v2f cr1 = WirB[0]*lo0 + WirB[1]*hi0 + WirB[2]*lo1 + WirB[3]*hi1;
            v2f cz0 = WizA[0]*lo0 + WizA[1]*hi0 + WizA[2]*lo1 + WizA[3]*hi1;
            v2f cz1 = WizB[0]*lo0 + WizB[1]*hi0 + WizB[2]*lo1 + WizB[3]*hi1;
            v2f cn0 = WinA[0]*lo0 + WinA[1]*hi0 + WinA[2]*lo1 + WinA[3]*hi1;
            v2f cn1 = WinB[0]*lo0 + WinB[1]*hi0 + WinB[2]*lo1 + WinB[3]*hi1;
            crA = cr0.x + cr0.y;  crB = cr1.x + cr1.y;
            czA = cz0.x + cz0.y;  czB = cz1.x + cz1.y;
            cnA = cn0.x + cn0.y;  cnB = cn1.x + cn1.y;

            if (own) sh_t0[jm] = fmaf(dt, k3, hj);
        }
        __syncthreads();                                   // B3

        // ---- P4: k4 dot; h_ode ----
        float hode = 0.0f;
        {
            float rA, rB;
            dot2(WnA, WnB, t04, rA, rB);
            float k4 = fast_tanh(red8_split(rA, rB, low) + bn_s);
            hode = fmaf(dt * (1.0f / 6.0f),
                        (k1 + 2.0f * k2) + (2.0f * k3 + k4), hj);
            if (own) sh_t1[jm] = hode;                     // t1 = h_ode vector
        }
        __syncthreads();                                   // B4

        // ---- P5: hidden-gate dots + combine (input partials folded pre-reduce) --
        {
            float4 v0 = t14[ks*4+0], v1 = t14[ks*4+1], v2 = t14[ks*4+2], v3 = t14[ks*4+3];
            v2f l0 = {v0.x,v0.y}, u0 = {v0.z,v0.w};
            v2f l1 = {v1.x,v1.y}, u1 = {v1.z,v1.w};
            v2f l2 = {v2.x,v2.y}, u2 = {v2.z,v2.w};
            v2f l3 = {v3.x,v3.y}, u3 = {v3.z,v3.w};
            v2f arA = WhrA[0]*l0 + WhrA[1]*u0 + WhrA[2]*l1 + WhrA[3]*u1
                    + WhrA[4]*l2 + WhrA[5]*u2 + WhrA[6]*l3 + WhrA[7]*u3;
            v2f arB = WhrB[0]*l0 + WhrB[1]*u0 + WhrB[2]*l1 + WhrB[3]*u1
                    + WhrB[4]*l2 + WhrB[5]*u2 + WhrB[6]*l3 + WhrB[7]*u3;
            v2f azA = WhzA[0]*l0 + WhzA[1]*u0 + WhzA[2]*l1 + WhzA[3]*u1
                    + WhzA[4]*l2 + WhzA[5]*u2 + WhzA[6]*l3 + WhzA[7]*u3;
            v2f azB = WhzB[0]*l0 + WhzB[1]*u0 + WhzB[2]*l1 + WhzB[3]*u1
                    + WhzB[4]*l2 + WhzB[5]*u2 + WhzB[6]*l3 + WhzB[7]*u3;
            v2f anA = WhnA[0]*l0 + WhnA[1]*u0 + WhnA[2]*l1 + WhnA[3]*u1
                    + WhnA[4]*l2 + WhnA[5]*u2 + WhnA[6]*l3 + WhnA[7]*u3;
            v2f anB = WhnB[0]*l0 + WhnB[1]*u0 + WhnB[2]*l1 + WhnB[3]*u1
                    + WhnB[4]*l2 + WhnB[5]*u2 + WhnB[6]*l3 + WhnB[7]*u3;

            float r_ = red8_split((arA.x + arA.y) + crA, (arB.x + arB.y) + crB, low);
            float z_ = red8_split((azA.x + azA.y) + czA, (azB.x + azB.y) + czB, low);
            float hn = red8_split(anA.x + anA.y, anB.x + anB.y, low);
            float in_ = red8_split(cnA, cnB, low);

            float rr = fast_sigmoid(r_ + br_s);
            float zz = fast_sigmoid(z_ + bz_s);
            float nn = fast_tanh(fmaf(rr, hn + bh_s, in_ + bi_s));
            float hnew = fmaf(zz, hode - nn, nn);          // (1-z)n + z*h_ode
            hj = hnew;                                      // valid on owners
            if (own) sh_h[jm] = hnew;
        }
        __syncthreads();                                   // B5
    }

    // ---- epilogue: out[T-1] from final h ----
    {
        float4 v0 = h4[ks*4+0], v1 = h4[ks*4+1], v2 = h4[ks*4+2], v3 = h4[ks*4+3];
        v2f l0 = {v0.x,v0.y}, u0 = {v0.z,v0.w};
        v2f l1 = {v1.x,v1.y}, u1 = {v1.z,v1.w};
        v2f l2 = {v2.x,v2.y}, u2 = {v2.z,v2.w};
        v2f l3 = {v3.x,v3.y}, u3 = {v3.z,v3.w};
        v2f ao = Wo[0]*l0 + Wo[1]*u0 + Wo[2]*l1 + Wo[3]*u1
               + Wo[4]*l2 + Wo[5]*u2 + Wo[6]*l3 + Wo[7]*u3;
        float o = red8(ao.x + ao.y) + bo;
        if (ks == 0) obase[(size_t)(TSTEP - 1) * DIN + jp] = o;
    }
}

extern "C" void kernel_launch(void* const* d_in, const int* in_sizes, int n_in,
                              void* d_out, int out_size, void* d_ws, size_t ws_size,
                              hipStream_t stream) {
    (void)in_sizes; (void)n_in; (void)d_ws; (void)ws_size; (void)out_size;
    const float* x      = (const float*)d_in[0];
    const float* tp     = (const float*)d_in[1];
    const int*   mask   = (const int*)  d_in[2];
    const float* W_ih   = (const float*)d_in[3];
    const float* W_hh   = (const float*)d_in[4];
    const float* b_ih   = (const float*)d_in[5];
    const float* b_hh   = (const float*)d_in[6];
    const float* W_node = (const float*)d_in[7];
    const float* b_node = (const float*)d_in[8];
    const float* W_out  = (const float*)d_in[9];
    const float* b_out  = (const float*)d_in[10];
    float* outp = (float*)d_out;

    gruode_kernel<<<NB, TB, 0, stream>>>(x, tp, mask, W_ih, W_hh, b_ih, b_hh,
                                         W_node, b_node, W_out, b_out, outp);
}

// Round 4
// 1104.545 us; speedup vs baseline: 1.6338x; 1.0305x over previous
//
#include <hip/hip_runtime.h>

// EncoderGRUODE: B=256, T=512, D_IN=64, H=128
// R6: R5 + bank-conflict fix (single surgical change).
//   R5 post-mortem: widening lanes to 16 CONTIGUOUS floats made dot reads
//   buf[ks*4+ii]; for fixed ii the wave's 8 float4 addrs sit at words
//   ks*16+ii*4 (mod 32) = 2 bank groups -> 4-way conflict on every
//   ds_read_b128 (8.39e7 cycles = ~640cy/CU-step, on the critical path).
//   Fix: strided slice ownership -- lane owns float4 columns {ks,8+ks,16+ks,
//   24+ks}; reads become buf[ii*8+ks] (fixed ii covers all 32 banks once,
//   the proven-clean R2/R4 pattern). Weight register slices re-mapped to
//   match; reductions/schedule/numerics unchanged.
// Predicted: conflicts ~0, VALUBusy ~65%, dur 1138 -> ~950us.

#define NB    256
#define TB    512
#define TSTEP 512
#define DIN   64
#define HD    128

typedef float v2f __attribute__((ext_vector_type(2)));

__device__ __forceinline__ float fast_tanh(float v) {
    float e = __expf(2.0f * v);
    return 1.0f - 2.0f / (e + 1.0f);
}
__device__ __forceinline__ float fast_sigmoid(float v) {
    return 1.0f / (1.0f + __expf(-v));
}

template<int PAT>
__device__ __forceinline__ float dpp_xadd(float v) {
    return v + __int_as_float(__builtin_amdgcn_update_dpp(
        0, __float_as_int(v), PAT, 0xF, 0xF, true));
}
template<int OFF>
__device__ __forceinline__ float swz(float v) {
    return __int_as_float(__builtin_amdgcn_ds_swizzle(__float_as_int(v), OFF));
}
// plain 8-lane all-lanes reduction (xor1, xor2, xor4)
__device__ __forceinline__ float red8(float v) {
    v = dpp_xadd<0xB1>(v);
    v = dpp_xadd<0x4E>(v);
    return v + swz<0x101F>(v);
}
// reduce two row-partials over the 8-lane group for the price of one:
// lanes with low=true end with rowA total, low=false with rowB total.
__device__ __forceinline__ float red8_split(float pA, float pB, bool low) {
    pA = dpp_xadd<0xB1>(pA);  pB = dpp_xadd<0xB1>(pB);
    pA = dpp_xadd<0x4E>(pA);  pB = dpp_xadd<0x4E>(pB);
    float keep = low ? pA : pB;
    float send = low ? pB : pA;
    return keep + swz<0x101F>(send);
}

__global__ __launch_bounds__(TB, 2) void gruode_kernel(
    const float* __restrict__ x,         // [B, T, DIN]
    const float* __restrict__ tp,        // [B, T] (row 0 used)
    const int*   __restrict__ samp_mask, // [T]
    const float* __restrict__ W_ih,      // [3H, DIN]
    const float* __restrict__ W_hh,      // [3H, H]
    const float* __restrict__ b_ih,      // [3H]
    const float* __restrict__ b_hh,      // [3H]
    const float* __restrict__ W_node,    // [H, H]
    const float* __restrict__ b_node,    // [H]
    const float* __restrict__ W_out,     // [DIN, H]
    const float* __restrict__ b_out,     // [DIN]
    float*       __restrict__ out)       // [B*T, DIN]
{
    const int t    = threadIdx.x;
    const int b    = blockIdx.x;
    const int jp   = t >> 3;              // row-pair index 0..63 (also out row)
    const int ks   = t & 7;               // strided k-slice 0..7
    const bool low = (ks & 4) == 0;       // owns rowA (2jp) vs rowB (2jp+1)
    const int jm   = 2 * jp + (ks >> 2);  // my hidden row after split-reduce
    const bool own = (ks & 3) == 0;       // writer lane for row jm

    __shared__ __align__(16) float sh_h [HD];
    __shared__ __align__(16) float sh_t0[HD];
    __shared__ __align__(16) float sh_t1[HD];
    __shared__ __align__(16) float sh_in[DIN];
    __shared__ __align__(16) float sh_po[DIN];
    __shared__ float sh_dt[TSTEP];
    __shared__ int   sh_mk[TSTEP];

    const float4* Wn4  = (const float4*)W_node;  // [128][32 f4]
    const float4* Whh4 = (const float4*)W_hh;    // [384][32 f4]
    const float4* Wih4 = (const float4*)W_ih;    // [384][16 f4]
    const float4* Wo4  = (const float4*)W_out;   // [64][32 f4]

    // ---- weights -> registers: 2 rows x strided 16-float slice ----
    // Lane owns float4 columns {ii*8 + ks, ii=0..3} of 32 (RK4/GRU-h/out rows)
    // and {ii*8 + ks, ii=0..1} of 16 (input rows).
    v2f WnA[8], WnB[8], WhrA[8], WhrB[8], WhzA[8], WhzB[8], WhnA[8], WhnB[8];
    #pragma unroll
    for (int ii = 0; ii < 4; ++ii) {
        float4 w;
        const int c = ii * 8 + ks;
        w = Wn4 [(2*jp  )*32 + c];        WnA [2*ii] = (v2f){w.x,w.y}; WnA [2*ii+1] = (v2f){w.z,w.w};
        w = Wn4 [(2*jp+1)*32 + c];        WnB [2*ii] = (v2f){w.x,w.y}; WnB [2*ii+1] = (v2f){w.z,w.w};
        w = Whh4[(0*HD + 2*jp  )*32 + c]; WhrA[2*ii] = (v2f){w.x,w.y}; WhrA[2*ii+1] = (v2f){w.z,w.w};
        w = Whh4[(0*HD + 2*jp+1)*32 + c]; WhrB[2*ii] = (v2f){w.x,w.y}; WhrB[2*ii+1] = (v2f){w.z,w.w};
        w = Whh4[(1*HD + 2*jp  )*32 + c]; WhzA[2*ii] = (v2f){w.x,w.y}; WhzA[2*ii+1] = (v2f){w.z,w.w};
        w = Whh4[(1*HD + 2*jp+1)*32 + c]; WhzB[2*ii] = (v2f){w.x,w.y}; WhzB[2*ii+1] = (v2f){w.z,w.w};
        w = Whh4[(2*HD + 2*jp  )*32 + c]; WhnA[2*ii] = (v2f){w.x,w.y}; WhnA[2*ii+1] = (v2f){w.z,w.w};
        w = Whh4[(2*HD + 2*jp+1)*32 + c]; WhnB[2*ii] = (v2f){w.x,w.y}; WhnB[2*ii+1] = (v2f){w.z,w.w};
    }
    v2f WirA[4], WirB[4], WizA[4], WizB[4], WinA[4], WinB[4], Wo[8];
    #pragma unroll
    for (int ii = 0; ii < 2; ++ii) {
        float4 w;
        const int c = ii * 8 + ks;
        w = Wih4[(0*HD + 2*jp  )*16 + c]; WirA[2*ii] = (v2f){w.x,w.y}; WirA[2*ii+1] = (v2f){w.z,w.w};
        w = Wih4[(0*HD + 2*jp+1)*16 + c]; WirB[2*ii] = (v2f){w.x,w.y}; WirB[2*ii+1] = (v2f){w.z,w.w};
        w = Wih4[(1*HD + 2*jp  )*16 + c]; WizA[2*ii] = (v2f){w.x,w.y}; WizA[2*ii+1] = (v2f){w.z,w.w};
        w = Wih4[(1*HD + 2*jp+1)*16 + c]; WizB[2*ii] = (v2f){w.x,w.y}; WizB[2*ii+1] = (v2f){w.z,w.w};
        w = Wih4[(2*HD + 2*jp  )*16 + c]; WinA[2*ii] = (v2f){w.x,w.y}; WinA[2*ii+1] = (v2f){w.z,w.w};
        w = Wih4[(2*HD + 2*jp+1)*16 + c]; WinB[2*ii] = (v2f){w.x,w.y}; WinB[2*ii+1] = (v2f){w.z,w.w};
    }
    #pragma unroll
    for (int ii = 0; ii < 4; ++ii) {      // out row jp, same strided slice as k1
        float4 w = Wo4[jp*32 + ii*8 + ks];
        Wo[2*ii] = (v2f){w.x,w.y}; Wo[2*ii+1] = (v2f){w.z,w.w};
    }
    // Pin: opaque to rematerialization (prevents L2 re-fetch).
    #pragma unroll
    for (int ii = 0; ii < 8; ++ii) {
        asm volatile("" : "+v"(WnA[ii]));  asm volatile("" : "+v"(WnB[ii]));
        asm volatile("" : "+v"(WhrA[ii])); asm volatile("" : "+v"(WhrB[ii]));
        asm volatile("" : "+v"(WhzA[ii])); asm volatile("" : "+v"(WhzB[ii]));
        asm volatile("" : "+v"(WhnA[ii])); asm volatile("" : "+v"(WhnB[ii]));
        asm volatile("" : "+v"(Wo[ii]));
    }
    #pragma unroll
    for (int ii = 0; ii < 4; ++ii) {
        asm volatile("" : "+v"(WirA[ii])); asm volatile("" : "+v"(WirB[ii]));
        asm volatile("" : "+v"(WizA[ii])); asm volatile("" : "+v"(WizB[ii]));
        asm volatile("" : "+v"(WinA[ii])); asm volatile("" : "+v"(WinB[ii]));
    }

    // per-row biases for my row jm; out bias for row jp
    const float bn_s = b_node[jm];
    const float br_s = b_ih[0*HD + jm] + b_hh[0*HD + jm];
    const float bz_s = b_ih[1*HD + jm] + b_hh[1*HD + jm];
    const float bi_s = b_ih[2*HD + jm];
    const float bh_s = b_hh[2*HD + jm];
    const float bo   = b_out[jp];

    if (t < HD) sh_h[t] = 0.0f;
    {   // dt/mask tables -> LDS once (per-step reads are uniform broadcasts)
        float tc = tp[t];
        float tq = (t == 0) ? tc - 0.01f : tp[t - 1];
        sh_dt[t] = tc - tq;
        sh_mk[t] = samp_mask[t];
    }

    const float* xbase = x   + (size_t)b * TSTEP * DIN;
    float*       obase = out + (size_t)b * TSTEP * DIN;
    float xr = (t < DIN) ? xbase[t] : 0.0f;

    __syncthreads();

    const float4* h4  = (const float4*)sh_h;
    const float4* t04 = (const float4*)sh_t0;
    const float4* t14 = (const float4*)sh_t1;
    const float4* in4 = (const float4*)sh_in;

    // 2-row strided dot over a 128-float LDS vector: for fixed ii, the wave's
    // 8 float4 addrs cover all 32 banks once (conflict-free).
    auto dot2 = [&](const v2f (&wA)[8], const v2f (&wB)[8], const float4* buf,
                    float& rA, float& rB) {
        v2f aA = {0.f,0.f}, bA = {0.f,0.f}, aB = {0.f,0.f}, bB = {0.f,0.f};
        #pragma unroll
        for (int ii = 0; ii < 4; ++ii) {
            float4 v = buf[ii*8 + ks];
            v2f lo = {v.x, v.y}, hi = {v.z, v.w};
            aA += wA[2*ii] * lo;  bA += wA[2*ii+1] * hi;
            aB += wB[2*ii] * lo;  bB += wB[2*ii+1] * hi;
        }
        v2f sA = aA + bA, sB = aB + bB;
        rA = sA.x + sA.y;  rB = sB.x + sB.y;
    };

    float hj = 0.0f;   // my row's h (meaningful on owner lanes)

    #pragma unroll 1
    for (int s = 0; s < TSTEP; ++s) {
        const float dt = sh_dt[s];
        const int   mc = sh_mk[s];
        float k1, k2, k3;

        // ---- P1: k1 dot + out matvec sharing the same sh_h loads ----
        {
            float4 v0 = h4[ks], v1 = h4[8+ks], v2 = h4[16+ks], v3 = h4[24+ks];
            v2f l0 = {v0.x,v0.y}, u0 = {v0.z,v0.w};
            v2f l1 = {v1.x,v1.y}, u1 = {v1.z,v1.w};
            v2f l2 = {v2.x,v2.y}, u2 = {v2.z,v2.w};
            v2f l3 = {v3.x,v3.y}, u3 = {v3.z,v3.w};
            v2f aA = WnA[0]*l0 + WnA[1]*u0 + WnA[2]*l1 + WnA[3]*u1
                   + WnA[4]*l2 + WnA[5]*u2 + WnA[6]*l3 + WnA[7]*u3;
            v2f aB = WnB[0]*l0 + WnB[1]*u0 + WnB[2]*l1 + WnB[3]*u1
                   + WnB[4]*l2 + WnB[5]*u2 + WnB[6]*l3 + WnB[7]*u3;
            v2f ao = Wo[0]*l0 + Wo[1]*u0 + Wo[2]*l1 + Wo[3]*u1
                   + Wo[4]*l2 + Wo[5]*u2 + Wo[6]*l3 + Wo[7]*u3;
            k1 = fast_tanh(red8_split(aA.x + aA.y, aB.x + aB.y, low) + bn_s);
            float o = red8(ao.x + ao.y) + bo;   // = h(s-1)@Wo^T + bo
            if (ks == 0) {
                sh_po[jp] = o;                   // prev_out for this step
                if (s > 0) obase[(size_t)(s - 1) * DIN + jp] = o;
            }
            if (own) sh_t0[jm] = fmaf(0.5f * dt, k1, hj);
        }
        __syncthreads();                                   // B1

        // ---- P2: build input vec; k2 dot; prefetch next-step x ----
        if (t < DIN) sh_in[t] = mc ? xr : sh_po[t];
        {
            float rA, rB;
            dot2(WnA, WnB, t04, rA, rB);
            k2 = fast_tanh(red8_split(rA, rB, low) + bn_s);
            if (own) sh_t1[jm] = fmaf(0.5f * dt, k2, hj);
        }
        {
            const int sn = (s + 1 < TSTEP) ? s + 1 : s;
            if (t < DIN) xr = xbase[(size_t)sn * DIN + t];
        }
        __syncthreads();                                   // B2

        // ---- P3: k3 dot + input-gate partial dots (reduction deferred) ----
        float crA, crB, czA, czB, cnA, cnB;
        {
            float rA, rB;
            dot2(WnA, WnB, t14, rA, rB);
            k3 = fast_tanh(red8_split(rA, rB, low) + bn_s);

            float4 v0 = in4[ks], v1 = in4[8 + ks];
            v2f lo0 = {v0.x,v0.y}, hi0 = {v0.z,v0.w};
            v2f lo1 = {v1.x,v1.y}, hi1 = {v1.z,v1.w};
            v2f cr0 = WirA[0]*lo0 + WirA[1]*hi0 + WirA[2]*lo1 + WirA[3]*hi1;
            v2f cr1 = WirB[0]*lo0 + WirB[1]*hi0 + WirB[2]*lo1 + WirB[3]*hi1;
            v2f cz0 = WizA[0]*lo0 + WizA[1]*hi0 + WizA[2]*lo1 + WizA[3]*hi1;
            v2f cz1 = WizB[0]*lo0 + WizB[1]*hi0 + WizB[2]*lo1 + WizB[3]*hi1;
            v2f cn0 = WinA[0]*lo0 + WinA[1]*hi0 + WinA[2]*lo1 + WinA[3]*hi1;
            v2f cn1 = WinB[0]*lo0 + WinB[1]*hi0 + WinB[2]*lo1 + WinB[3]*hi1;
            crA = cr0.x + cr0.y;  crB = cr1.x + cr1.y;
            czA = cz0.x + cz0.y;  czB = cz1.x + cz1.y;
            cnA = cn0.x + cn0.y;  cnB = cn1.x + cn1.y;

            if (own) sh_t0[jm] = fmaf(dt, k3, hj);
        }
        __syncthreads();                                   // B3

        // ---- P4: k4 dot; h_ode ----
        float hode = 0.0f;
        {
            float rA, rB;
            dot2(WnA, WnB, t04, rA, rB);
            float k4 = fast_tanh(red8_split(rA, rB, low) + bn_s);
            hode = fmaf(dt * (1.0f / 6.0f),
                        (k1 + 2.0f * k2) + (2.0f * k3 + k4), hj);
            if (own) sh_t1[jm] = hode;                     // t1 = h_ode vector
        }
        __syncthreads();                                   // B4

        // ---- P5: hidden-gate dots + combine (input partials folded pre-reduce) --
        {
            float4 v0 = t14[ks], v1 = t14[8+ks], v2 = t14[16+ks], v3 = t14[24+ks];
            v2f l0 = {v0.x,v0.y}, u0 = {v0.z,v0.w};
            v2f l1 = {v1.x,v1.y}, u1 = {v1.z,v1.w};
            v2f l2 = {v2.x,v2.y}, u2 = {v2.z,v2.w};
            v2f l3 = {v3.x,v3.y}, u3 = {v3.z,v3.w};
            v2f arA = WhrA[0]*l0 + WhrA[1]*u0 + WhrA[2]*l1 + WhrA[3]*u1
                    + WhrA[4]*l2 + WhrA[5]*u2 + WhrA[6]*l3 + WhrA[7]*u3;
            v2f arB = WhrB[0]*l0 + WhrB[1]*u0 + WhrB[2]*l1 + WhrB[3]*u1
                    + WhrB[4]*l2 + WhrB[5]*u2 + WhrB[6]*l3 + WhrB[7]*u3;
            v2f azA = WhzA[0]*l0 + WhzA[1]*u0 + WhzA[2]*l1 + WhzA[3]*u1
                    + WhzA[4]*l2 + WhzA[5]*u2 + WhzA[6]*l3 + WhzA[7]*u3;
            v2f azB = WhzB[0]*l0 + WhzB[1]*u0 + WhzB[2]*l1 + WhzB[3]*u1
                    + WhzB[4]*l2 + WhzB[5]*u2 + WhzB[6]*l3 + WhzB[7]*u3;
            v2f anA = WhnA[0]*l0 + WhnA[1]*u0 + WhnA[2]*l1 + WhnA[3]*u1
                    + WhnA[4]*l2 + WhnA[5]*u2 + WhnA[6]*l3 + WhnA[7]*u3;
            v2f anB = WhnB[0]*l0 + WhnB[1]*u0 + WhnB[2]*l1 + WhnB[3]*u1
                    + WhnB[4]*l2 + WhnB[5]*u2 + WhnB[6]*l3 + WhnB[7]*u3;

            float r_ = red8_split((arA.x + arA.y) + crA, (arB.x + arB.y) + crB, low);
            float z_ = red8_split((azA.x + azA.y) + czA, (azB.x + azB.y) + czB, low);
            float hn = red8_split(anA.x + anA.y, anB.x + anB.y, low);
            float in_ = red8_split(cnA, cnB, low);

            float rr = fast_sigmoid(r_ + br_s);
            float zz = fast_sigmoid(z_ + bz_s);
            float nn = fast_tanh(fmaf(rr, hn + bh_s, in_ + bi_s));
            float hnew = fmaf(zz, hode - nn, nn);          // (1-z)n + z*h_ode
            hj = hnew;                                      // valid on owners
            if (own) sh_h[jm] = hnew;
        }
        __syncthreads();                                   // B5
    }

    // ---- epilogue: out[T-1] from final h ----
    {
        float4 v0 = h4[ks], v1 = h4[8+ks], v2 = h4[16+ks], v3 = h4[24+ks];
        v2f l0 = {v0.x,v0.y}, u0 = {v0.z,v0.w};
        v2f l1 = {v1.x,v1.y}, u1 = {v1.z,v1.w};
        v2f l2 = {v2.x,v2.y}, u2 = {v2.z,v2.w};
        v2f l3 = {v3.x,v3.y}, u3 = {v3.z,v3.w};
        v2f ao = Wo[0]*l0 + Wo[1]*u0 + Wo[2]*l1 + Wo[3]*u1
               + Wo[4]*l2 + Wo[5]*u2 + Wo[6]*l3 + Wo[7]*u3;
        float o = red8(ao.x + ao.y) + bo;
        if (ks == 0) obase[(size_t)(TSTEP - 1) * DIN + jp] = o;
    }
}

extern "C" void kernel_launch(void* const* d_in, const int* in_sizes, int n_in,
                              void* d_out, int out_size, void* d_ws, size_t ws_size,
                              hipStream_t stream) {
    (void)in_sizes; (void)n_in; (void)d_ws; (void)ws_size; (void)out_size;
    const float* x      = (const float*)d_in[0];
    const float* tp     = (const float*)d_in[1];
    const int*   mask   = (const int*)  d_in[2];
    const float* W_ih   = (const float*)d_in[3];
    const float* W_hh   = (const float*)d_in[4];
    const float* b_ih   = (const float*)d_in[5];
    const float* b_hh   = (const float*)d_in[6];
    const float* W_node = (const float*)d_in[7];
    const float* b_node = (const float*)d_in[8];
    const float* W_out  = (const float*)d_in[9];
    const float* b_out  = (const float*)d_in[10];
    float* outp = (float*)d_out;

    gruode_kernel<<<NB, TB, 0, stream>>>(x, tp, mask, W_ih, W_hh, b_ih, b_hh,
                                         W_node, b_node, W_out, b_out, outp);
}

// Round 5
// 1099.094 us; speedup vs baseline: 1.6419x; 1.0050x over previous
//
#include <hip/hip_runtime.h>

// EncoderGRUODE: B=256, T=512, D_IN=64, H=128
// R7 = R6 + relaxed barriers (single surgical change).
//   R6 post-mortem: conflicts -> 0 as predicted but only -34us => LDS conflicts
//   were overlapped. Step = 5400cy: ~3300 VALU-busy + ~2100 idle. Occupancy is
//   grid-capped (256 blocks = 256 CUs, 8 waves/CU). New theory for the idle:
//   __syncthreads drains vmcnt(0) -- the P1 out-store ack and the P2 x-prefetch
//   (HBM/L2 latency) get serialized into B1/B2 EVERY step, stalling all waves.
//   Fix: LDS-only barrier = s_waitcnt lgkmcnt(0) + s_barrier (vmcnt stays
//   outstanding across barriers). Safe because all cross-lane traffic is LDS;
//   the only vmcnt ops are the out store (never read on-device) and the x load
//   (same-thread register consume one full step later; compiler auto-waits).
// Predicted: VALU busy-time flat (~670us) => VALUBusy ~70%, dur 1104 -> ~930us.

#define NB    256
#define TB    512
#define TSTEP 512
#define DIN   64
#define HD    128

typedef float v2f __attribute__((ext_vector_type(2)));

__device__ __forceinline__ float fast_tanh(float v) {
    float e = __expf(2.0f * v);
    return 1.0f - 2.0f / (e + 1.0f);
}
__device__ __forceinline__ float fast_sigmoid(float v) {
    return 1.0f / (1.0f + __expf(-v));
}

// LDS-only block barrier: drain lgkm (our ds_writes visible), sync, and fence
// code motion on both sides. Deliberately does NOT drain vmcnt -- global
// stores/prefetches stay in flight across the barrier (the point of R7).
__device__ __forceinline__ void sync_lds() {
    asm volatile("s_waitcnt lgkmcnt(0)" ::: "memory");
    __builtin_amdgcn_s_barrier();
    asm volatile("" ::: "memory");
}

template<int PAT>
__device__ __forceinline__ float dpp_xadd(float v) {
    return v + __int_as_float(__builtin_amdgcn_update_dpp(
        0, __float_as_int(v), PAT, 0xF, 0xF, true));
}
template<int OFF>
__device__ __forceinline__ float swz(float v) {
    return __int_as_float(__builtin_amdgcn_ds_swizzle(__float_as_int(v), OFF));
}
// plain 8-lane all-lanes reduction (xor1, xor2, xor4)
__device__ __forceinline__ float red8(float v) {
    v = dpp_xadd<0xB1>(v);
    v = dpp_xadd<0x4E>(v);
    return v + swz<0x101F>(v);
}
// reduce two row-partials over the 8-lane group for the price of one:
// lanes with low=true end with rowA total, low=false with rowB total.
__device__ __forceinline__ float red8_split(float pA, float pB, bool low) {
    pA = dpp_xadd<0xB1>(pA);  pB = dpp_xadd<0xB1>(pB);
    pA = dpp_xadd<0x4E>(pA);  pB = dpp_xadd<0x4E>(pB);
    float keep = low ? pA : pB;
    float send = low ? pB : pA;
    return keep + swz<0x101F>(send);
}

__global__ __launch_bounds__(TB, 2) void gruode_kernel(
    const float* __restrict__ x,         // [B, T, DIN]
    const float* __restrict__ tp,        // [B, T] (row 0 used)
    const int*   __restrict__ samp_mask, // [T]
    const float* __restrict__ W_ih,      // [3H, DIN]
    const float* __restrict__ W_hh,      // [3H, H]
    const float* __restrict__ b_ih,      // [3H]
    const float* __restrict__ b_hh,      // [3H]
    const float* __restrict__ W_node,    // [H, H]
    const float* __restrict__ b_node,    // [H]
    const float* __restrict__ W_out,     // [DIN, H]
    const float* __restrict__ b_out,     // [DIN]
    float*       __restrict__ out)       // [B*T, DIN]
{
    const int t    = threadIdx.x;
    const int b    = blockIdx.x;
    const int jp   = t >> 3;              // row-pair index 0..63 (also out row)
    const int ks   = t & 7;               // strided k-slice 0..7
    const bool low = (ks & 4) == 0;       // owns rowA (2jp) vs rowB (2jp+1)
    const int jm   = 2 * jp + (ks >> 2);  // my hidden row after split-reduce
    const bool own = (ks & 3) == 0;       // writer lane for row jm

    __shared__ __align__(16) float sh_h [HD];
    __shared__ __align__(16) float sh_t0[HD];
    __shared__ __align__(16) float sh_t1[HD];
    __shared__ __align__(16) float sh_in[DIN];
    __shared__ __align__(16) float sh_po[DIN];
    __shared__ float sh_dt[TSTEP];
    __shared__ int   sh_mk[TSTEP];

    const float4* Wn4  = (const float4*)W_node;  // [128][32 f4]
    const float4* Whh4 = (const float4*)W_hh;    // [384][32 f4]
    const float4* Wih4 = (const float4*)W_ih;    // [384][16 f4]
    const float4* Wo4  = (const float4*)W_out;   // [64][32 f4]

    // ---- weights -> registers: 2 rows x strided 16-float slice ----
    // Lane owns float4 columns {ii*8 + ks, ii=0..3} of 32 (RK4/GRU-h/out rows)
    // and {ii*8 + ks, ii=0..1} of 16 (input rows). Conflict-free read pattern.
    v2f WnA[8], WnB[8], WhrA[8], WhrB[8], WhzA[8], WhzB[8], WhnA[8], WhnB[8];
    #pragma unroll
    for (int ii = 0; ii < 4; ++ii) {
        float4 w;
        const int c = ii * 8 + ks;
        w = Wn4 [(2*jp  )*32 + c];        WnA [2*ii] = (v2f){w.x,w.y}; WnA [2*ii+1] = (v2f){w.z,w.w};
        w = Wn4 [(2*jp+1)*32 + c];        WnB [2*ii] = (v2f){w.x,w.y}; WnB [2*ii+1] = (v2f){w.z,w.w};
        w = Whh4[(0*HD + 2*jp  )*32 + c]; WhrA[2*ii] = (v2f){w.x,w.y}; WhrA[2*ii+1] = (v2f){w.z,w.w};
        w = Whh4[(0*HD + 2*jp+1)*32 + c]; WhrB[2*ii] = (v2f){w.x,w.y}; WhrB[2*ii+1] = (v2f){w.z,w.w};
        w = Whh4[(1*HD + 2*jp  )*32 + c]; WhzA[2*ii] = (v2f){w.x,w.y}; WhzA[2*ii+1] = (v2f){w.z,w.w};
        w = Whh4[(1*HD + 2*jp+1)*32 + c]; WhzB[2*ii] = (v2f){w.x,w.y}; WhzB[2*ii+1] = (v2f){w.z,w.w};
        w = Whh4[(2*HD + 2*jp  )*32 + c]; WhnA[2*ii] = (v2f){w.x,w.y}; WhnA[2*ii+1] = (v2f){w.z,w.w};
        w = Whh4[(2*HD + 2*jp+1)*32 + c]; WhnB[2*ii] = (v2f){w.x,w.y}; WhnB[2*ii+1] = (v2f){w.z,w.w};
    }
    v2f WirA[4], WirB[4], WizA[4], WizB[4], WinA[4], WinB[4], Wo[8];
    #pragma unroll
    for (int ii = 0; ii < 2; ++ii) {
        float4 w;
        const int c = ii * 8 + ks;
        w = Wih4[(0*HD + 2*jp  )*16 + c]; WirA[2*ii] = (v2f){w.x,w.y}; WirA[2*ii+1] = (v2f){w.z,w.w};
        w = Wih4[(0*HD + 2*jp+1)*16 + c]; WirB[2*ii] = (v2f){w.x,w.y}; WirB[2*ii+1] = (v2f){w.z,w.w};
        w = Wih4[(1*HD + 2*jp  )*16 + c]; WizA[2*ii] = (v2f){w.x,w.y}; WizA[2*ii+1] = (v2f){w.z,w.w};
        w = Wih4[(1*HD + 2*jp+1)*16 + c]; WizB[2*ii] = (v2f){w.x,w.y}; WizB[2*ii+1] = (v2f){w.z,w.w};
        w = Wih4[(2*HD + 2*jp  )*16 + c]; WinA[2*ii] = (v2f){w.x,w.y}; WinA[2*ii+1] = (v2f){w.z,w.w};
        w = Wih4[(2*HD + 2*jp+1)*16 + c]; WinB[2*ii] = (v2f){w.x,w.y}; WinB[2*ii+1] = (v2f){w.z,w.w};
    }
    #pragma unroll
    for (int ii = 0; ii < 4; ++ii) {      // out row jp, same strided slice as k1
        float4 w = Wo4[jp*32 + ii*8 + ks];
        Wo[2*ii] = (v2f){w.x,w.y}; Wo[2*ii+1] = (v2f){w.z,w.w};
    }
    // Pin: opaque to rematerialization (prevents L2 re-fetch).
    #pragma unroll
    for (int ii = 0; ii < 8; ++ii) {
        asm volatile("" : "+v"(WnA[ii]));  asm volatile("" : "+v"(WnB[ii]));
        asm volatile("" : "+v"(WhrA[ii])); asm volatile("" : "+v"(WhrB[ii]));
        asm volatile("" : "+v"(WhzA[ii])); asm volatile("" : "+v"(WhzB[ii]));
        asm volatile("" : "+v"(WhnA[ii])); asm volatile("" : "+v"(WhnB[ii]));
        asm volatile("" : "+v"(Wo[ii]));
    }
    #pragma unroll
    for (int ii = 0; ii < 4; ++ii) {
        asm volatile("" : "+v"(WirA[ii])); asm volatile("" : "+v"(WirB[ii]));
        asm volatile("" : "+v"(WizA[ii])); asm volatile("" : "+v"(WizB[ii]));
        asm volatile("" : "+v"(WinA[ii])); asm volatile("" : "+v"(WinB[ii]));
    }

    // per-row biases for my row jm; out bias for row jp
    const float bn_s = b_node[jm];
    const float br_s = b_ih[0*HD + jm] + b_hh[0*HD + jm];
    const float bz_s = b_ih[1*HD + jm] + b_hh[1*HD + jm];
    const float bi_s = b_ih[2*HD + jm];
    const float bh_s = b_hh[2*HD + jm];
    const float bo   = b_out[jp];

    if (t < HD) sh_h[t] = 0.0f;
    {   // dt/mask tables -> LDS once (per-step reads are uniform broadcasts)
        float tc = tp[t];
        float tq = (t == 0) ? tc - 0.01f : tp[t - 1];
        sh_dt[t] = tc - tq;
        sh_mk[t] = samp_mask[t];
    }

    const float* xbase = x   + (size_t)b * TSTEP * DIN;
    float*       obase = out + (size_t)b * TSTEP * DIN;
    float xr = (t < DIN) ? xbase[t] : 0.0f;

    sync_lds();

    const float4* h4  = (const float4*)sh_h;
    const float4* t04 = (const float4*)sh_t0;
    const float4* t14 = (const float4*)sh_t1;
    const float4* in4 = (const float4*)sh_in;

    // 2-row strided dot over a 128-float LDS vector: for fixed ii, the wave's
    // 8 float4 addrs cover all 32 banks once (conflict-free).
    auto dot2 = [&](const v2f (&wA)[8], const v2f (&wB)[8], const float4* buf,
                    float& rA, float& rB) {
        v2f aA = {0.f,0.f}, bA = {0.f,0.f}, aB = {0.f,0.f}, bB = {0.f,0.f};
        #pragma unroll
        for (int ii = 0; ii < 4; ++ii) {
            float4 v = buf[ii*8 + ks];
            v2f lo = {v.x, v.y}, hi = {v.z, v.w};
            aA += wA[2*ii] * lo;  bA += wA[2*ii+1] * hi;
            aB += wB[2*ii] * lo;  bB += wB[2*ii+1] * hi;
        }
        v2f sA = aA + bA, sB = aB + bB;
        rA = sA.x + sA.y;  rB = sB.x + sB.y;
    };

    float hj = 0.0f;   // my row's h (meaningful on owner lanes)

    #pragma unroll 1
    for (int s = 0; s < TSTEP; ++s) {
        const float dt = sh_dt[s];
        const int   mc = sh_mk[s];
        float k1, k2, k3;

        // ---- P1: k1 dot + out matvec sharing the same sh_h loads ----
        {
            float4 v0 = h4[ks], v1 = h4[8+ks], v2 = h4[16+ks], v3 = h4[24+ks];
            v2f l0 = {v0.x,v0.y}, u0 = {v0.z,v0.w};
            v2f l1 = {v1.x,v1.y}, u1 = {v1.z,v1.w};
            v2f l2 = {v2.x,v2.y}, u2 = {v2.z,v2.w};
            v2f l3 = {v3.x,v3.y}, u3 = {v3.z,v3.w};
            v2f aA = WnA[0]*l0 + WnA[1]*u0 + WnA[2]*l1 + WnA[3]*u1
                   + WnA[4]*l2 + WnA[5]*u2 + WnA[6]*l3 + WnA[7]*u3;
            v2f aB = WnB[0]*l0 + WnB[1]*u0 + WnB[2]*l1 + WnB[3]*u1
                   + WnB[4]*l2 + WnB[5]*u2 + WnB[6]*l3 + WnB[7]*u3;
            v2f ao = Wo[0]*l0 + Wo[1]*u0 + Wo[2]*l1 + Wo[3]*u1
                   + Wo[4]*l2 + Wo[5]*u2 + Wo[6]*l3 + Wo[7]*u3;
            k1 = fast_tanh(red8_split(aA.x + aA.y, aB.x + aB.y, low) + bn_s);
            float o = red8(ao.x + ao.y) + bo;   // = h(s-1)@Wo^T + bo
            if (ks == 0) {
                sh_po[jp] = o;                   // prev_out for this step
                if (s > 0) obase[(size_t)(s - 1) * DIN + jp] = o;
            }
            if (own) sh_t0[jm] = fmaf(0.5f * dt, k1, hj);
        }
        sync_lds();                                        // B1 (no vmcnt drain)

        // ---- P2: build input vec; k2 dot; prefetch next-step x ----
        if (t < DIN) sh_in[t] = mc ? xr : sh_po[t];
        {
            float rA, rB;
            dot2(WnA, WnB, t04, rA, rB);
            k2 = fast_tanh(red8_split(rA, rB, low) + bn_s);
            if (own) sh_t1[jm] = fmaf(0.5f * dt, k2, hj);
        }
        {
            const int sn = (s + 1 < TSTEP) ? s + 1 : s;
            if (t < DIN) xr = xbase[(size_t)sn * DIN + t];
        }
        sync_lds();                                        // B2 (x load in flight)

        // ---- P3: k3 dot + input-gate partial dots (reduction deferred) ----
        float crA, crB, czA, czB, cnA, cnB;
        {
            float rA, rB;
            dot2(WnA, WnB, t14, rA, rB);
            k3 = fast_tanh(red8_split(rA, rB, low) + bn_s);

            float4 v0 = in4[ks], v1 = in4[8 + ks];
            v2f lo0 = {v0.x,v0.y}, hi0 = {v0.z,v0.w};
            v2f lo1 = {v1.x,v1.y}, hi1 = {v1.z,v1.w};
            v2f cr0 = WirA[0]*lo0 + WirA[1]*hi0 + WirA[2]*lo1 + WirA[3]*hi1;
            v2f cr1 = WirB[0]*lo0 + WirB[1]*hi0 + WirB[2]*lo1 + WirB[3]*hi1;
            v2f cz0 = WizA[0]*lo0 + WizA[1]*hi0 + WizA[2]*lo1 + WizA[3]*hi1;
            v2f cz1 = WizB[0]*lo0 + WizB[1]*hi0 + WizB[2]*lo1 + WizB[3]*hi1;
            v2f cn0 = WinA[0]*lo0 + WinA[1]*hi0 + WinA[2]*lo1 + WinA[3]*hi1;
            v2f cn1 = WinB[0]*lo0 + WinB[1]*hi0 + WinB[2]*lo1 + WinB[3]*hi1;
            crA = cr0.x + cr0.y;  crB = cr1.x + cr1.y;
            czA = cz0.x + cz0.y;  czB = cz1.x + cz1.y;
            cnA = cn0.x + cn0.y;  cnB = cn1.x + cn1.y;

            if (own) sh_t0[jm] = fmaf(dt, k3, hj);
        }
        sync_lds();                                        // B3

        // ---- P4: k4 dot; h_ode ----
        float hode = 0.0f;
        {
            float rA, rB;
            dot2(WnA, WnB, t04, rA, rB);
            float k4 = fast_tanh(red8_split(rA, rB, low) + bn_s);
            hode = fmaf(dt * (1.0f / 6.0f),
                        (k1 + 2.0f * k2) + (2.0f * k3 + k4), hj);
            if (own) sh_t1[jm] = hode;                     // t1 = h_ode vector
        }
        sync_lds();                                        // B4

        // ---- P5: hidden-gate dots + combine (input partials folded pre-reduce) --
        {
            float4 v0 = t14[ks], v1 = t14[8+ks], v2 = t14[16+ks], v3 = t14[24+ks];
            v2f l0 = {v0.x,v0.y}, u0 = {v0.z,v0.w};
            v2f l1 = {v1.x,v1.y}, u1 = {v1.z,v1.w};
            v2f l2 = {v2.x,v2.y}, u2 = {v2.z,v2.w};
            v2f l3 = {v3.x,v3.y}, u3 = {v3.z,v3.w};
            v2f arA = WhrA[0]*l0 + WhrA[1]*u0 + WhrA[2]*l1 + WhrA[3]*u1
                    + WhrA[4]*l2 + WhrA[5]*u2 + WhrA[6]*l3 + WhrA[7]*u3;
            v2f arB = WhrB[0]*l0 + WhrB[1]*u0 + WhrB[2]*l1 + WhrB[3]*u1
                    + WhrB[4]*l2 + WhrB[5]*u2 + WhrB[6]*l3 + WhrB[7]*u3;
            v2f azA = WhzA[0]*l0 + WhzA[1]*u0 + WhzA[2]*l1 + WhzA[3]*u1
                    + WhzA[4]*l2 + WhzA[5]*u2 + WhzA[6]*l3 + WhzA[7]*u3;
            v2f azB = WhzB[0]*l0 + WhzB[1]*u0 + WhzB[2]*l1 + WhzB[3]*u1
                    + WhzB[4]*l2 + WhzB[5]*u2 + WhzB[6]*l3 + WhzB[7]*u3;
            v2f anA = WhnA[0]*l0 + WhnA[1]*u0 + WhnA[2]*l1 + WhnA[3]*u1
                    + WhnA[4]*l2 + WhnA[5]*u2 + WhnA[6]*l3 + WhnA[7]*u3;
            v2f anB = WhnB[0]*l0 + WhnB[1]*u0 + WhnB[2]*l1 + WhnB[3]*u1
                    + WhnB[4]*l2 + WhnB[5]*u2 + WhnB[6]*l3 + WhnB[7]*u3;

            float r_ = red8_split((arA.x + arA.y) + crA, (arB.x + arB.y) + crB, low);
            float z_ = red8_split((azA.x + azA.y) + czA, (azB.x + azB.y) + czB, low);
            float hn = red8_split(anA.x + anA.y, anB.x + anB.y, low);
            float in_ = red8_split(cnA, cnB, low);

            float rr = fast_sigmoid(r_ + br_s);
            float zz = fast_sigmoid(z_ + bz_s);
            float nn = fast_tanh(fmaf(rr, hn + bh_s, in_ + bi_s));
            float hnew = fmaf(zz, hode - nn, nn);          // (1-z)n + z*h_ode
            hj = hnew;                                      // valid on owners
            if (own) sh_h[jm] = hnew;
        }
        sync_lds();                                        // B5
    }

    // ---- epilogue: out[T-1] from final h ----
    {
        float4 v0 = h4[ks], v1 = h4[8+ks], v2 = h4[16+ks], v3 = h4[24+ks];
        v2f l0 = {v0.x,v0.y}, u0 = {v0.z,v0.w};
        v2f l1 = {v1.x,v1.y}, u1 = {v1.z,v1.w};
        v2f l2 = {v2.x,v2.y}, u2 = {v2.z,v2.w};
        v2f l3 = {v3.x,v3.y}, u3 = {v3.z,v3.w};
        v2f ao = Wo[0]*l0 + Wo[1]*u0 + Wo[2]*l1 + Wo[3]*u1
               + Wo[4]*l2 + Wo[5]*u2 + Wo[6]*l3 + Wo[7]*u3;
        float o = red8(ao.x + ao.y) + bo;
        if (ks == 0) obase[(size_t)(TSTEP - 1) * DIN + jp] = o;
    }
}

extern "C" void kernel_launch(void* const* d_in, const int* in_sizes, int n_in,
                              void* d_out, int out_size, void* d_ws, size_t ws_size,
                              hipStream_t stream) {
    (void)in_sizes; (void)n_in; (void)d_ws; (void)ws_size; (void)out_size;
    const float* x      = (const float*)d_in[0];
    const float* tp     = (const float*)d_in[1];
    const int*   mask   = (const int*)  d_in[2];
    const float* W_ih   = (const float*)d_in[3];
    const float* W_hh   = (const float*)d_in[4];
    const float* b_ih   = (const float*)d_in[5];
    const float* b_hh   = (const float*)d_in[6];
    const float* W_node = (const float*)d_in[7];
    const float* b_node = (const float*)d_in[8];
    const float* W_out  = (const float*)d_in[9];
    const float* b_out  = (const float*)d_in[10];
    float* outp = (float*)d_out;

    gruode_kernel<<<NB, TB, 0, stream>>>(x, tp, mask, W_ih, W_hh, b_ih, b_hh,
                                         W_node, b_node, W_out, b_out, outp);
}